// Round 8
// baseline (647.769 us; speedup 1.0000x reference)
//
#include <hip/hip_runtime.h>
#include <hip/hip_bf16.h>

// GCN 2-layer forward. CSR pull-aggregation (one node per lane-group; round-4
// proved serializing nodes in the gather costs 3.4x — TLP is the currency).
// gemm1: A = register-prefetch distance 2 (never in LDS, wave-private rows),
// B = LDS double-buffer with distance-1 reg staging; issue order keeps A loads
// outstanding across the barrier. Rounds 6/7 proved distance-1 staging exposes
// full load latency at every step regardless of occupancy.
// N=100000, F_IN=512, HID=128, C=40, E=1.6M

#define F_IN 512
#define HID  128
#define NC   40

typedef __attribute__((ext_vector_type(8))) short bf16x8;
typedef __attribute__((ext_vector_type(4))) float f32x4v;

__device__ __forceinline__ ushort f2bf(float f) {
    union { float f; unsigned u; } x; x.f = f;
    unsigned r = x.u + 0x7FFFu + ((x.u >> 16) & 1u);   // round-to-nearest-even
    return (ushort)(r >> 16);
}
__device__ __forceinline__ float bf2f(ushort u) {
    return __uint_as_float((unsigned)u << 16);
}

// ---------------- degree count (real edges only) ----------------
__global__ void count_deg(const int* __restrict__ dst, int E, unsigned* __restrict__ cnt) {
    int t = blockIdx.x * blockDim.x + threadIdx.x;
    if (t < E) atomicAdd(&cnt[dst[t]], 1u);
}

// ---------------- prefix sum over cnt -> offs (exclusive), fused dis ---------
__global__ __launch_bounds__(1024) void scan_block(const unsigned* __restrict__ cnt,
                                                   unsigned* __restrict__ offs,
                                                   unsigned* __restrict__ bsums,
                                                   float* __restrict__ dis, int N) {
    __shared__ unsigned s[1024];
    int tid = threadIdx.x;
    int i = blockIdx.x * 1024 + tid;
    unsigned v = (i < N) ? cnt[i] : 0u;
    if (i < N) dis[i] = rsqrtf((float)v + 1.0f);   // +1 = self loop
    s[tid] = v;
    __syncthreads();
    #pragma unroll
    for (int d = 1; d < 1024; d <<= 1) {
        unsigned t = (tid >= d) ? s[tid - d] : 0u;
        __syncthreads();
        s[tid] += t;
        __syncthreads();
    }
    if (i < N) offs[i] = s[tid] - v;
    if (tid == 1023) bsums[blockIdx.x] = s[1023];
}

__global__ __launch_bounds__(1024) void scan_bsums(unsigned* __restrict__ bsums, int nb) {
    __shared__ unsigned s[1024];
    int tid = threadIdx.x;
    unsigned v = (tid < nb) ? bsums[tid] : 0u;
    s[tid] = v;
    __syncthreads();
    #pragma unroll
    for (int d = 1; d < 1024; d <<= 1) {
        unsigned t = (tid >= d) ? s[tid - d] : 0u;
        __syncthreads();
        s[tid] += t;
        __syncthreads();
    }
    if (tid < nb) bsums[tid] = s[tid] - v;   // exclusive
}

__global__ __launch_bounds__(1024) void scan_add(unsigned* __restrict__ offs,
                                                 const unsigned* __restrict__ bsums,
                                                 int N, unsigned total) {
    int i = blockIdx.x * 1024 + threadIdx.x;
    if (i < N) offs[i] += bsums[blockIdx.x];
    if (i == 0) offs[N] = total;
}

// ---------------- CSR fill (real edges only) ----------------
__global__ void fill_csr(const int* __restrict__ src, const int* __restrict__ dst,
                         const unsigned* __restrict__ offs, unsigned* __restrict__ cursor,
                         int* __restrict__ col, int E) {
    int t = blockIdx.x * blockDim.x + threadIdx.x;
    if (t >= E) return;
    int s = src[t], d = dst[t];
    unsigned pos = offs[d] + atomicAdd(&cursor[d], 1u);
    col[pos] = s;
}

// ---------------- merged weight pack ----------------
// W1p: [s(16)][kb(4)][n(128)][j(8)], k = s*32+kb*8+j   (65536 elems)
// W2p: [ks(4)][kb(4)][n(48)][j(8)],  k = ks*32+kb*8+j  (6144 elems, n>=40 -> 0)
__global__ void packW(const float* __restrict__ W1, const float* __restrict__ W2,
                      ushort* __restrict__ W1p, ushort* __restrict__ W2p) {
    int t = blockIdx.x * 256 + threadIdx.x;
    if (t < 65536) {
        int j = t & 7, n = (t >> 3) & 127, kb = (t >> 10) & 3, s = t >> 12;
        int k = s * 32 + kb * 8 + j;
        W1p[t] = f2bf(W1[(size_t)k * HID + n]);
    } else {
        int q = t - 65536;
        if (q < 6144) {
            int j = q & 7;
            int i2 = q >> 3;
            int n = i2 % 48;
            int i3 = i2 / 48;
            int kb = i3 & 3, ks = i3 >> 2;
            int k = ks * 32 + kb * 8 + j;
            float v = (n < NC) ? W2[(size_t)k * NC + n] : 0.f;
            W2p[q] = f2bf(v);
        }
    }
}

// ------- GEMM1 MFMA: h1s[N,128] = (bf16(x) @ W1) * dis[row]  (bf16 out) -----
// 64-row tile, 4 waves x 16 rows. A: register prefetch, distance 2, no LDS.
// B: LDS double-buffer; global->reg at step s, reg->LDS at step s+1.
// Issue order per step: consume-A(conv), consume-bv(ds_write), reload bv,
// reload av, MFMA, barrier — waiting on bv never drains the younger A loads.
__global__ __launch_bounds__(256) void gemm1_mfma(const float* __restrict__ A,
                                                  const ushort* __restrict__ Bp,
                                                  const float* __restrict__ dis,
                                                  ushort* __restrict__ C, int N) {
    __shared__ __align__(16) ushort Bs[2][4096];      // 8 KB each
    const int tid  = threadIdx.x;
    const int wave = tid >> 6;
    const int lane = tid & 63;
    const int quad = lane >> 4;
    const int mr   = lane & 15;
    const int bm   = blockIdx.x * 64;
    const int row  = bm + wave * 16 + mr;
    const bool ok  = row < N;
    const float* aptr = A + (size_t)(ok ? row : 0) * F_IN + quad * 8;

    f32x4v acc[8];
    #pragma unroll
    for (int t = 0; t < 8; t++) acc[t] = (f32x4v){0.f, 0.f, 0.f, 0.f};

    const float4 z4 = make_float4(0.f, 0.f, 0.f, 0.f);
    float4 av[2][2];
    uint4 bv0, bv1;

    // preload A steps 0,1 (distance-2 pipeline)
    av[0][0] = ok ? *(const float4*)(aptr)      : z4;
    av[0][1] = ok ? *(const float4*)(aptr + 4)  : z4;
    av[1][0] = ok ? *(const float4*)(aptr + 32) : z4;
    av[1][1] = ok ? *(const float4*)(aptr + 36) : z4;
    // stage B tile 0 directly to LDS; prefetch tile 1 into regs
    ((uint4*)Bs[0])[tid]       = ((const uint4*)Bp)[tid];
    ((uint4*)Bs[0])[tid + 256] = ((const uint4*)Bp)[tid + 256];
    {
        const uint4* bp = (const uint4*)(Bp + 4096);
        bv0 = bp[tid];
        bv1 = bp[tid + 256];
    }
    __syncthreads();

    for (int s = 0; s < 16; s++) {
        // 1. consume A regs for step s -> bf16 fragment
        float4 a0 = av[s & 1][0], a1 = av[s & 1][1];
        __align__(16) ushort ta[8];
        ta[0]=f2bf(a0.x); ta[1]=f2bf(a0.y); ta[2]=f2bf(a0.z); ta[3]=f2bf(a0.w);
        ta[4]=f2bf(a1.x); ta[5]=f2bf(a1.y); ta[6]=f2bf(a1.z); ta[7]=f2bf(a1.w);
        bf16x8 fa = *(const bf16x8*)ta;
        // 2. consume bv: write B tile s+1 into the other LDS buffer
        if (s < 15) {
            ((uint4*)Bs[(s + 1) & 1])[tid]       = bv0;
            ((uint4*)Bs[(s + 1) & 1])[tid + 256] = bv1;
        }
        // 3. reload bv <- B tile s+2
        if (s < 14) {
            const uint4* bp = (const uint4*)(Bp + (size_t)(s + 2) * 4096);
            bv0 = bp[tid];
            bv1 = bp[tid + 256];
        }
        // 4. reload av <- A step s+2
        if (s + 2 < 16) {
            av[s & 1][0] = ok ? *(const float4*)(aptr + (s + 2) * 32)     : z4;
            av[s & 1][1] = ok ? *(const float4*)(aptr + (s + 2) * 32 + 4) : z4;
        }
        // 5. MFMA from LDS buffer s&1 (filled at step s-1)
        {
            const ushort* bb = Bs[s & 1] + quad * 1024 + mr * 8;
            #pragma unroll
            for (int t = 0; t < 8; t++) {
                bf16x8 b = *(const bf16x8*)&bb[t * 128];
                acc[t] = __builtin_amdgcn_mfma_f32_16x16x32_bf16(fa, b, acc[t], 0, 0, 0);
            }
        }
        __syncthreads();
    }

    // epilogue: C/D layout col=mr, row=quad*4+reg; scale by dis[row]
    #pragma unroll
    for (int rr = 0; rr < 4; rr++) {
        int r = bm + wave * 16 + quad * 4 + rr;
        if (r < N) {
            float ds = dis[r];
            #pragma unroll
            for (int t = 0; t < 8; t++)
                C[(size_t)r * HID + t * 16 + mr] = f2bf(acc[t][rr] * ds);
        }
    }
}

// ------- agg1: one node per 16-lane group, uint4 gathers, x8 unroll ----------
// out[node] = dis[node] * (h1s[node] + sum_{s in N(node)} h1s[s])
__global__ __launch_bounds__(256) void agg1_k(const ushort* __restrict__ h,
                                              const int* __restrict__ col,
                                              const unsigned* __restrict__ offs,
                                              const float* __restrict__ dis,
                                              ushort* __restrict__ out, int N) {
    int node = blockIdx.x * 16 + (threadIdx.x >> 4);
    if (node >= N) return;
    int lane = threadIdx.x & 15;
    const size_t coff = (size_t)lane * 8;
    float a[8];
    {   // self
        uint4 v = *(const uint4*)(h + (size_t)node * HID + coff);
        const ushort* u = (const ushort*)&v;
        #pragma unroll
        for (int j = 0; j < 8; j++) a[j] = bf2f(u[j]);
    }
    unsigned p0 = offs[node], p1 = offs[node + 1];
    unsigned p = p0;
    for (; p + 8 <= p1; p += 8) {
        int s0 = col[p],   s1 = col[p+1], s2 = col[p+2], s3 = col[p+3];
        int s4 = col[p+4], s5 = col[p+5], s6 = col[p+6], s7 = col[p+7];
        uint4 v0 = *(const uint4*)(h + (size_t)s0 * HID + coff);
        uint4 v1 = *(const uint4*)(h + (size_t)s1 * HID + coff);
        uint4 v2 = *(const uint4*)(h + (size_t)s2 * HID + coff);
        uint4 v3 = *(const uint4*)(h + (size_t)s3 * HID + coff);
        uint4 v4 = *(const uint4*)(h + (size_t)s4 * HID + coff);
        uint4 v5 = *(const uint4*)(h + (size_t)s5 * HID + coff);
        uint4 v6 = *(const uint4*)(h + (size_t)s6 * HID + coff);
        uint4 v7 = *(const uint4*)(h + (size_t)s7 * HID + coff);
        const ushort* u0 = (const ushort*)&v0;
        const ushort* u1 = (const ushort*)&v1;
        const ushort* u2 = (const ushort*)&v2;
        const ushort* u3 = (const ushort*)&v3;
        const ushort* u4 = (const ushort*)&v4;
        const ushort* u5 = (const ushort*)&v5;
        const ushort* u6 = (const ushort*)&v6;
        const ushort* u7 = (const ushort*)&v7;
        #pragma unroll
        for (int j = 0; j < 8; j++) {
            float t0 = bf2f(u0[j]) + bf2f(u1[j]);
            float t1 = bf2f(u2[j]) + bf2f(u3[j]);
            float t2 = bf2f(u4[j]) + bf2f(u5[j]);
            float t3 = bf2f(u6[j]) + bf2f(u7[j]);
            a[j] += (t0 + t1) + (t2 + t3);
        }
    }
    for (; p < p1; ++p) {
        int s = col[p];
        uint4 v = *(const uint4*)(h + (size_t)s * HID + coff);
        const ushort* u = (const ushort*)&v;
        #pragma unroll
        for (int j = 0; j < 8; j++) a[j] += bf2f(u[j]);
    }
    float dd = dis[node];
    __align__(16) ushort o[8];
    #pragma unroll
    for (int j = 0; j < 8; j++) o[j] = f2bf(a[j] * dd);
    *(uint4*)(out + (size_t)node * HID + coff) = *(const uint4*)o;
}

// ------- GEMM2 MFMA: h2s[N,40] = (relu(agg1 + b1) @ W2) * dis[row] (bf16) ---
__global__ __launch_bounds__(256) void gemm2_mfma(const ushort* __restrict__ A,
                                                  const float* __restrict__ b1,
                                                  const ushort* __restrict__ W2p,
                                                  const float* __restrict__ dis,
                                                  ushort* __restrict__ h2, int N) {
    __shared__ __align__(16) ushort As[128 * 136];
    __shared__ __align__(16) ushort Bs[6144];
    const int tid = threadIdx.x;
    const int bm = blockIdx.x * 128;

    {
        const uint4* s4 = (const uint4*)W2p;
        uint4* d4 = (uint4*)Bs;
        #pragma unroll
        for (int i = 0; i < 3; i++) d4[tid + i * 256] = s4[tid + i * 256];
    }
    {
        const int r  = tid >> 1;
        const int hh = tid & 1;
        const int row = bm + r;
        const float* brow = b1 + hh * 64;
        if (row < N) {
            const ushort* arow = A + (size_t)row * HID + hh * 64;
            #pragma unroll
            for (int i = 0; i < 8; i++) {
                uint4 raw = *(const uint4*)(arow + i * 8);
                const ushort* u = (const ushort*)&raw;
                __align__(16) ushort tmp[8];
                #pragma unroll
                for (int j = 0; j < 8; j++)
                    tmp[j] = f2bf(fmaxf(bf2f(u[j]) + brow[i * 8 + j], 0.f));
                *(uint4*)&As[r * 136 + hh * 64 + i * 8] = *(const uint4*)tmp;
            }
        } else {
            #pragma unroll
            for (int i = 0; i < 8; i++) {
                uint4 zz = {0, 0, 0, 0};
                *(uint4*)&As[r * 136 + hh * 64 + i * 8] = zz;
            }
        }
    }
    __syncthreads();

    const int wave = tid >> 6;
    const int lane = tid & 63;
    const int quad = lane >> 4;
    const int mr   = lane & 15;
    f32x4v acc[2][3];
    #pragma unroll
    for (int i = 0; i < 2; i++)
        #pragma unroll
        for (int t = 0; t < 3; t++)
            acc[i][t] = (f32x4v){0.f, 0.f, 0.f, 0.f};
    #pragma unroll
    for (int ks = 0; ks < 4; ks++) {
        bf16x8 a0 = *(const bf16x8*)&As[(wave * 32 + mr) * 136 + ks * 32 + quad * 8];
        bf16x8 a1 = *(const bf16x8*)&As[(wave * 32 + 16 + mr) * 136 + ks * 32 + quad * 8];
        #pragma unroll
        for (int t = 0; t < 3; t++) {
            bf16x8 b = *(const bf16x8*)&Bs[((ks * 4 + quad) * 48 + t * 16 + mr) * 8];
            acc[0][t] = __builtin_amdgcn_mfma_f32_16x16x32_bf16(a0, b, acc[0][t], 0, 0, 0);
            acc[1][t] = __builtin_amdgcn_mfma_f32_16x16x32_bf16(a1, b, acc[1][t], 0, 0, 0);
        }
    }
    #pragma unroll
    for (int i = 0; i < 2; i++) {
        #pragma unroll
        for (int rr = 0; rr < 4; rr++) {
            int node = bm + wave * 32 + i * 16 + quad * 4 + rr;
            if (node < N) {
                float ds = dis[node];
                #pragma unroll
                for (int t = 0; t < 3; t++) {
                    int c = t * 16 + mr;
                    if (c < NC)
                        h2[(size_t)node * NC + c] = f2bf(acc[i][t][rr] * ds);
                }
            }
        }
    }
}

// ------- agg2 + b2 + log_softmax: one node per 8-lane group, 5 active lanes --
// logits = dis[node] * (h2s[node] + sum h2s[s]) + b2
__global__ __launch_bounds__(256) void agg2_ls(const ushort* __restrict__ h2,
                                               const int* __restrict__ col,
                                               const unsigned* __restrict__ offs,
                                               const float* __restrict__ dis,
                                               const float* __restrict__ b2,
                                               float* __restrict__ out, int N) {
    int node = blockIdx.x * 32 + (threadIdx.x >> 3);
    if (node >= N) return;
    int lane = threadIdx.x & 7;
    const bool act = lane < 5;
    const size_t coff = (size_t)lane * 8;
    float a[8] = {};
    if (act) {
        uint4 v = *(const uint4*)(h2 + (size_t)node * NC + coff);
        const ushort* u = (const ushort*)&v;
        #pragma unroll
        for (int j = 0; j < 8; j++) a[j] = bf2f(u[j]);
    }
    unsigned p0 = offs[node], p1 = offs[node + 1];
    unsigned p = p0;
    for (; p + 4 <= p1; p += 4) {
        int s0 = col[p], s1 = col[p + 1], s2 = col[p + 2], s3 = col[p + 3];
        if (act) {
            uint4 v0 = *(const uint4*)(h2 + (size_t)s0 * NC + coff);
            uint4 v1 = *(const uint4*)(h2 + (size_t)s1 * NC + coff);
            uint4 v2 = *(const uint4*)(h2 + (size_t)s2 * NC + coff);
            uint4 v3 = *(const uint4*)(h2 + (size_t)s3 * NC + coff);
            const ushort* u0 = (const ushort*)&v0;
            const ushort* u1 = (const ushort*)&v1;
            const ushort* u2 = (const ushort*)&v2;
            const ushort* u3 = (const ushort*)&v3;
            #pragma unroll
            for (int j = 0; j < 8; j++)
                a[j] += (bf2f(u0[j]) + bf2f(u1[j])) + (bf2f(u2[j]) + bf2f(u3[j]));
        }
    }
    for (; p < p1; ++p) {
        int s = col[p];
        if (act) {
            uint4 v = *(const uint4*)(h2 + (size_t)s * NC + coff);
            const ushort* u = (const ushort*)&v;
            #pragma unroll
            for (int j = 0; j < 8; j++) a[j] += bf2f(u[j]);
        }
    }
    float dd = dis[node];
    float l[8];
    float m = -1e30f;
    if (act) {
        #pragma unroll
        for (int j = 0; j < 8; j++) {
            l[j] = a[j] * dd + b2[lane * 8 + j];
            m = fmaxf(m, l[j]);
        }
    }
    #pragma unroll
    for (int d = 1; d < 8; d <<= 1) m = fmaxf(m, __shfl_xor(m, d, 8));
    float s = 0.f;
    if (act) {
        #pragma unroll
        for (int j = 0; j < 8; j++) s += __expf(l[j] - m);
    }
    #pragma unroll
    for (int d = 1; d < 8; d <<= 1) s += __shfl_xor(s, d, 8);
    float lse = m + __logf(s);
    if (act) {
        float* op = out + (size_t)node * NC + lane * 8;
        *(float4*)op       = make_float4(l[0]-lse, l[1]-lse, l[2]-lse, l[3]-lse);
        *(float4*)(op + 4) = make_float4(l[4]-lse, l[5]-lse, l[6]-lse, l[7]-lse);
    }
}

extern "C" void kernel_launch(void* const* d_in, const int* in_sizes, int n_in,
                              void* d_out, int out_size, void* d_ws, size_t ws_size,
                              hipStream_t stream) {
    const float* x  = (const float*)d_in[0];
    const int*   ei = (const int*)d_in[1];
    const float* W1 = (const float*)d_in[2];
    const float* b1 = (const float*)d_in[3];
    const float* W2 = (const float*)d_in[4];
    const float* b2 = (const float*)d_in[5];
    float* out = (float*)d_out;

    const int N = in_sizes[0] / F_IN;     // 100000
    const int E = in_sizes[1] / 2;        // 1600000
    const int* src = ei;
    const int* dst = ei + E;

    // ---- workspace layout ----
    char* ws = (char*)d_ws;
    size_t o = 0;
    unsigned* cnt  = (unsigned*)(ws + o); o += (size_t)N * 4;
    unsigned* cur  = (unsigned*)(ws + o); o += (size_t)N * 4;   // contiguous w/ cnt
    float*    dis  = (float*)   (ws + o); o += (size_t)N * 4;
    unsigned* offs = (unsigned*)(ws + o); o += (size_t)(N + 4) * 4;
    unsigned* bsums= (unsigned*)(ws + o); o += 4096;
    int*      col  = (int*)     (ws + o); o += (size_t)E * 4;
    o = (o + 15) & ~(size_t)15;
    ushort*   W1p  = (ushort*)  (ws + o); o += (size_t)F_IN * HID * 2;   // 128 KB
    o = (o + 15) & ~(size_t)15;
    ushort*   W2p  = (ushort*)  (ws + o); o += 6144 * 2;                 // 12 KB
    o = (o + 15) & ~(size_t)15;
    ushort*   h1   = (ushort*)  (ws + o); o += (size_t)N * HID * 2;      // 25.6 MB
    o = (o + 15) & ~(size_t)15;
    ushort*   ag1  = (ushort*)  (ws + o); o += (size_t)N * HID * 2;      // 25.6 MB
    o = (o + 15) & ~(size_t)15;
    ushort*   h2   = (ushort*)  (ws + o); o += (size_t)N * NC * 2;       // 8 MB

    const int nb = (N + 1023) / 1024;

    // degree + CSR build (cnt and cur zeroed in one memset — contiguous)
    hipMemsetAsync(cnt, 0, (size_t)N * 8, stream);
    count_deg<<<(E + 255) / 256, 256, 0, stream>>>(dst, E, cnt);
    scan_block<<<nb, 1024, 0, stream>>>(cnt, offs, bsums, dis, N);
    scan_bsums<<<1, 1024, 0, stream>>>(bsums, nb);
    scan_add<<<nb, 1024, 0, stream>>>(offs, bsums, N, (unsigned)E);
    fill_csr<<<(E + 255) / 256, 256, 0, stream>>>(src, dst, offs, cur, col, E);

    // weight packs (merged)
    packW<<<(65536 + 6144 + 255) / 256, 256, 0, stream>>>(W1, W2, W1p, W2p);

    // layer 1
    gemm1_mfma<<<(N + 63) / 64, 256, 0, stream>>>(x, W1p, dis, h1, N);
    agg1_k<<<(N + 15) / 16, 256, 0, stream>>>(h1, col, offs, dis, ag1, N);

    // layer 2
    gemm2_mfma<<<(N + 127) / 128, 256, 0, stream>>>(ag1, b1, W2p, dis, h2, N);
    agg2_ls<<<(N + 31) / 32, 256, 0, stream>>>(h2, col, offs, dis, b2, out, N);
}

// Round 9
// 616.774 us; speedup vs baseline: 1.0503x; 1.0503x over previous
//
#include <hip/hip_runtime.h>
#include <hip/hip_bf16.h>

// GCN 2-layer forward. CSR pull-aggregation (one node per lane-group).
// GEMMs are BARRIER-FREE and LDS-FREE: per-wave row ownership, A register-
// prefetch distance 2, B fragments read directly from L2-resident packed
// weights. Rounds 6-8 proved any per-step __syncthreads drains vmcnt(0) and
// defeats every software pipeline (m97-plateau); the fix is no barriers.
// N=100000, F_IN=512, HID=128, C=40, E=1.6M

#define F_IN 512
#define HID  128
#define NC   40

typedef __attribute__((ext_vector_type(8))) short bf16x8;
typedef __attribute__((ext_vector_type(4))) float f32x4v;

__device__ __forceinline__ ushort f2bf(float f) {
    union { float f; unsigned u; } x; x.f = f;
    unsigned r = x.u + 0x7FFFu + ((x.u >> 16) & 1u);   // round-to-nearest-even
    return (ushort)(r >> 16);
}
__device__ __forceinline__ float bf2f(ushort u) {
    return __uint_as_float((unsigned)u << 16);
}
__device__ __forceinline__ bf16x8 cvt8(float4 lo, float4 hi) {
    __align__(16) ushort t[8];
    t[0]=f2bf(lo.x); t[1]=f2bf(lo.y); t[2]=f2bf(lo.z); t[3]=f2bf(lo.w);
    t[4]=f2bf(hi.x); t[5]=f2bf(hi.y); t[6]=f2bf(hi.z); t[7]=f2bf(hi.w);
    return *(const bf16x8*)t;
}

// ---------------- degree count (real edges only) ----------------
__global__ void count_deg(const int* __restrict__ dst, int E, unsigned* __restrict__ cnt) {
    int t = blockIdx.x * blockDim.x + threadIdx.x;
    if (t < E) atomicAdd(&cnt[dst[t]], 1u);
}

// ---------------- prefix sum over cnt -> offs (exclusive), fused dis ---------
__global__ __launch_bounds__(1024) void scan_block(const unsigned* __restrict__ cnt,
                                                   unsigned* __restrict__ offs,
                                                   unsigned* __restrict__ bsums,
                                                   float* __restrict__ dis, int N) {
    __shared__ unsigned s[1024];
    int tid = threadIdx.x;
    int i = blockIdx.x * 1024 + tid;
    unsigned v = (i < N) ? cnt[i] : 0u;
    if (i < N) dis[i] = rsqrtf((float)v + 1.0f);   // +1 = self loop
    s[tid] = v;
    __syncthreads();
    #pragma unroll
    for (int d = 1; d < 1024; d <<= 1) {
        unsigned t = (tid >= d) ? s[tid - d] : 0u;
        __syncthreads();
        s[tid] += t;
        __syncthreads();
    }
    if (i < N) offs[i] = s[tid] - v;
    if (tid == 1023) bsums[blockIdx.x] = s[1023];
}

__global__ __launch_bounds__(1024) void scan_bsums(unsigned* __restrict__ bsums, int nb) {
    __shared__ unsigned s[1024];
    int tid = threadIdx.x;
    unsigned v = (tid < nb) ? bsums[tid] : 0u;
    s[tid] = v;
    __syncthreads();
    #pragma unroll
    for (int d = 1; d < 1024; d <<= 1) {
        unsigned t = (tid >= d) ? s[tid - d] : 0u;
        __syncthreads();
        s[tid] += t;
        __syncthreads();
    }
    if (tid < nb) bsums[tid] = s[tid] - v;   // exclusive
}

__global__ __launch_bounds__(1024) void scan_add(unsigned* __restrict__ offs,
                                                 const unsigned* __restrict__ bsums,
                                                 int N, unsigned total) {
    int i = blockIdx.x * 1024 + threadIdx.x;
    if (i < N) offs[i] += bsums[blockIdx.x];
    if (i == 0) offs[N] = total;
}

// ---------------- CSR fill (real edges only) ----------------
__global__ void fill_csr(const int* __restrict__ src, const int* __restrict__ dst,
                         const unsigned* __restrict__ offs, unsigned* __restrict__ cursor,
                         int* __restrict__ col, int E) {
    int t = blockIdx.x * blockDim.x + threadIdx.x;
    if (t >= E) return;
    int s = src[t], d = dst[t];
    unsigned pos = offs[d] + atomicAdd(&cursor[d], 1u);
    col[pos] = s;
}

// ---------------- merged weight pack ----------------
// W1p: [s(16)][kb(4)][n(128)][j(8)], k = s*32+kb*8+j   (65536 elems)
// W2p: [ks(4)][kb(4)][n(48)][j(8)],  k = ks*32+kb*8+j  (6144 elems, n>=40 -> 0)
__global__ void packW(const float* __restrict__ W1, const float* __restrict__ W2,
                      ushort* __restrict__ W1p, ushort* __restrict__ W2p) {
    int t = blockIdx.x * 256 + threadIdx.x;
    if (t < 65536) {
        int j = t & 7, n = (t >> 3) & 127, kb = (t >> 10) & 3, s = t >> 12;
        int k = s * 32 + kb * 8 + j;
        W1p[t] = f2bf(W1[(size_t)k * HID + n]);
    } else {
        int q = t - 65536;
        if (q < 6144) {
            int j = q & 7;
            int i2 = q >> 3;
            int n = i2 % 48;
            int i3 = i2 / 48;
            int kb = i3 & 3, ks = i3 >> 2;
            int k = ks * 32 + kb * 8 + j;
            float v = (n < NC) ? W2[(size_t)k * NC + n] : 0.f;
            W2p[q] = f2bf(v);
        }
    }
}

// ------- GEMM1 MFMA, barrier-free: h1s[N,128] = (bf16(x) @ W1) * dis[row] ---
// Each wave owns 32 rows (2 M16 fragments). A: fp32 from global, register
// prefetch distance 2, convert in-reg. B: 16B fragment loads straight from
// L2-resident W1p (128 KB). No LDS, no __syncthreads -> no vmcnt(0) drains.
__global__ __launch_bounds__(256) void gemm1_mfma(const float* __restrict__ A,
                                                  const ushort* __restrict__ Bp,
                                                  const float* __restrict__ dis,
                                                  ushort* __restrict__ C, int N) {
    const int tid  = threadIdx.x;
    const int wave = tid >> 6;
    const int lane = tid & 63;
    const int quad = lane >> 4;
    const int mr   = lane & 15;
    const int base = (blockIdx.x * 4 + wave) * 32;
    if (base >= N) return;
    const int r0 = base + mr;
    const int r1 = base + 16 + mr;
    const bool ok0 = r0 < N, ok1 = r1 < N;
    const float* ap0 = A + (size_t)(ok0 ? r0 : 0) * F_IN + quad * 8;
    const float* ap1 = A + (size_t)(ok1 ? r1 : 0) * F_IN + quad * 8;
    const ushort* bp = Bp + quad * 1024 + mr * 8;   // + s*4096 + t*128

    f32x4v acc0[8], acc1[8];
    #pragma unroll
    for (int t = 0; t < 8; t++) {
        acc0[t] = (f32x4v){0.f, 0.f, 0.f, 0.f};
        acc1[t] = (f32x4v){0.f, 0.f, 0.f, 0.f};
    }

    // A prefetch regs: [buf][r0lo, r0hi, r1lo, r1hi]
    float4 av[2][4];
    #pragma unroll
    for (int b = 0; b < 2; b++) {
        av[b][0] = *(const float4*)(ap0 + b * 32);
        av[b][1] = *(const float4*)(ap0 + b * 32 + 4);
        av[b][2] = *(const float4*)(ap1 + b * 32);
        av[b][3] = *(const float4*)(ap1 + b * 32 + 4);
    }

    for (int s = 0; s < 16; s++) {
        bf16x8 fa0 = cvt8(av[s & 1][0], av[s & 1][1]);
        bf16x8 fa1 = cvt8(av[s & 1][2], av[s & 1][3]);
        if (s < 14) {   // reload this buffer with step s+2 (distance 2)
            av[s & 1][0] = *(const float4*)(ap0 + (s + 2) * 32);
            av[s & 1][1] = *(const float4*)(ap0 + (s + 2) * 32 + 4);
            av[s & 1][2] = *(const float4*)(ap1 + (s + 2) * 32);
            av[s & 1][3] = *(const float4*)(ap1 + (s + 2) * 32 + 4);
        }
        const ushort* bs = bp + s * 4096;
        #pragma unroll
        for (int t = 0; t < 8; t++) {
            bf16x8 b = *(const bf16x8*)(bs + t * 128);
            acc0[t] = __builtin_amdgcn_mfma_f32_16x16x32_bf16(fa0, b, acc0[t], 0, 0, 0);
            acc1[t] = __builtin_amdgcn_mfma_f32_16x16x32_bf16(fa1, b, acc1[t], 0, 0, 0);
        }
    }

    // epilogue: C/D layout col=t*16+mr, row=quad*4+rr; scale by dis[row]
    #pragma unroll
    for (int rr = 0; rr < 4; rr++) {
        int ra = base + quad * 4 + rr;
        if (ra < N) {
            float ds = dis[ra];
            #pragma unroll
            for (int t = 0; t < 8; t++)
                C[(size_t)ra * HID + t * 16 + mr] = f2bf(acc0[t][rr] * ds);
        }
        int rb = base + 16 + quad * 4 + rr;
        if (rb < N) {
            float ds = dis[rb];
            #pragma unroll
            for (int t = 0; t < 8; t++)
                C[(size_t)rb * HID + t * 16 + mr] = f2bf(acc1[t][rr] * ds);
        }
    }
}

// ------- agg1: one node per 16-lane group, uint4 gathers, x8 unroll ----------
// out[node] = bf16( relu( dis[node] * (h1s[node] + sum h1s[s]) + b1 ) )
// (bias+relu fused here so gemm2 is a pure bf16 GEMM)
__global__ __launch_bounds__(256) void agg1_k(const ushort* __restrict__ h,
                                              const int* __restrict__ col,
                                              const unsigned* __restrict__ offs,
                                              const float* __restrict__ dis,
                                              const float* __restrict__ b1,
                                              ushort* __restrict__ out, int N) {
    int node = blockIdx.x * 16 + (threadIdx.x >> 4);
    if (node >= N) return;
    int lane = threadIdx.x & 15;
    const size_t coff = (size_t)lane * 8;
    float a[8];
    {   // self
        uint4 v = *(const uint4*)(h + (size_t)node * HID + coff);
        const ushort* u = (const ushort*)&v;
        #pragma unroll
        for (int j = 0; j < 8; j++) a[j] = bf2f(u[j]);
    }
    unsigned p0 = offs[node], p1 = offs[node + 1];
    unsigned p = p0;
    for (; p + 8 <= p1; p += 8) {
        int s0 = col[p],   s1 = col[p+1], s2 = col[p+2], s3 = col[p+3];
        int s4 = col[p+4], s5 = col[p+5], s6 = col[p+6], s7 = col[p+7];
        uint4 v0 = *(const uint4*)(h + (size_t)s0 * HID + coff);
        uint4 v1 = *(const uint4*)(h + (size_t)s1 * HID + coff);
        uint4 v2 = *(const uint4*)(h + (size_t)s2 * HID + coff);
        uint4 v3 = *(const uint4*)(h + (size_t)s3 * HID + coff);
        uint4 v4 = *(const uint4*)(h + (size_t)s4 * HID + coff);
        uint4 v5 = *(const uint4*)(h + (size_t)s5 * HID + coff);
        uint4 v6 = *(const uint4*)(h + (size_t)s6 * HID + coff);
        uint4 v7 = *(const uint4*)(h + (size_t)s7 * HID + coff);
        const ushort* u0 = (const ushort*)&v0;
        const ushort* u1 = (const ushort*)&v1;
        const ushort* u2 = (const ushort*)&v2;
        const ushort* u3 = (const ushort*)&v3;
        const ushort* u4 = (const ushort*)&v4;
        const ushort* u5 = (const ushort*)&v5;
        const ushort* u6 = (const ushort*)&v6;
        const ushort* u7 = (const ushort*)&v7;
        #pragma unroll
        for (int j = 0; j < 8; j++) {
            float t0 = bf2f(u0[j]) + bf2f(u1[j]);
            float t1 = bf2f(u2[j]) + bf2f(u3[j]);
            float t2 = bf2f(u4[j]) + bf2f(u5[j]);
            float t3 = bf2f(u6[j]) + bf2f(u7[j]);
            a[j] += (t0 + t1) + (t2 + t3);
        }
    }
    for (; p < p1; ++p) {
        int s = col[p];
        uint4 v = *(const uint4*)(h + (size_t)s * HID + coff);
        const ushort* u = (const ushort*)&v;
        #pragma unroll
        for (int j = 0; j < 8; j++) a[j] += bf2f(u[j]);
    }
    float dd = dis[node];
    float4 bb0 = *(const float4*)(b1 + lane * 8);
    float4 bb1 = *(const float4*)(b1 + lane * 8 + 4);
    const float bb[8] = {bb0.x, bb0.y, bb0.z, bb0.w, bb1.x, bb1.y, bb1.z, bb1.w};
    __align__(16) ushort o[8];
    #pragma unroll
    for (int j = 0; j < 8; j++) o[j] = f2bf(fmaxf(a[j] * dd + bb[j], 0.f));
    *(uint4*)(out + (size_t)node * HID + coff) = *(const uint4*)o;
}

// ------- GEMM2 MFMA, barrier-free: h2s[N,40] = (ag1 @ W2) * dis[row] (bf16) -
// ag1 already has bias+relu applied. Pure bf16 fragment-direct, no LDS.
__global__ __launch_bounds__(256) void gemm2_mfma(const ushort* __restrict__ A,
                                                  const ushort* __restrict__ W2p,
                                                  const float* __restrict__ dis,
                                                  ushort* __restrict__ h2, int N) {
    const int tid  = threadIdx.x;
    const int wave = tid >> 6;
    const int lane = tid & 63;
    const int quad = lane >> 4;
    const int mr   = lane & 15;
    const int base = (blockIdx.x * 4 + wave) * 32;
    if (base >= N) return;
    const int r0 = base + mr;
    const int r1 = base + 16 + mr;
    const bool ok0 = r0 < N, ok1 = r1 < N;
    const ushort* ap0 = A + (size_t)(ok0 ? r0 : 0) * HID + quad * 8;
    const ushort* ap1 = A + (size_t)(ok1 ? r1 : 0) * HID + quad * 8;
    const ushort* bp = W2p + quad * 384 + mr * 8;   // + ks*1536 + t*128

    f32x4v acc0[3], acc1[3];
    #pragma unroll
    for (int t = 0; t < 3; t++) {
        acc0[t] = (f32x4v){0.f, 0.f, 0.f, 0.f};
        acc1[t] = (f32x4v){0.f, 0.f, 0.f, 0.f};
    }
    #pragma unroll
    for (int ks = 0; ks < 4; ks++) {
        bf16x8 a0 = *(const bf16x8*)(ap0 + ks * 32);
        bf16x8 a1 = *(const bf16x8*)(ap1 + ks * 32);
        #pragma unroll
        for (int t = 0; t < 3; t++) {
            bf16x8 b = *(const bf16x8*)(bp + ks * 1536 + t * 128);
            acc0[t] = __builtin_amdgcn_mfma_f32_16x16x32_bf16(a0, b, acc0[t], 0, 0, 0);
            acc1[t] = __builtin_amdgcn_mfma_f32_16x16x32_bf16(a1, b, acc1[t], 0, 0, 0);
        }
    }
    #pragma unroll
    for (int rr = 0; rr < 4; rr++) {
        int ra = base + quad * 4 + rr;
        if (ra < N) {
            float ds = dis[ra];
            #pragma unroll
            for (int t = 0; t < 3; t++) {
                int c = t * 16 + mr;
                if (c < NC) h2[(size_t)ra * NC + c] = f2bf(acc0[t][rr] * ds);
            }
        }
        int rb = base + 16 + quad * 4 + rr;
        if (rb < N) {
            float ds = dis[rb];
            #pragma unroll
            for (int t = 0; t < 3; t++) {
                int c = t * 16 + mr;
                if (c < NC) h2[(size_t)rb * NC + c] = f2bf(acc1[t][rr] * ds);
            }
        }
    }
}

// ------- agg2 + b2 + log_softmax: one node per 8-lane group, 5 active lanes --
// logits = dis[node] * (h2s[node] + sum h2s[s]) + b2
__global__ __launch_bounds__(256) void agg2_ls(const ushort* __restrict__ h2,
                                               const int* __restrict__ col,
                                               const unsigned* __restrict__ offs,
                                               const float* __restrict__ dis,
                                               const float* __restrict__ b2,
                                               float* __restrict__ out, int N) {
    int node = blockIdx.x * 32 + (threadIdx.x >> 3);
    if (node >= N) return;
    int lane = threadIdx.x & 7;
    const bool act = lane < 5;
    const size_t coff = (size_t)lane * 8;
    float a[8] = {};
    if (act) {
        uint4 v = *(const uint4*)(h2 + (size_t)node * NC + coff);
        const ushort* u = (const ushort*)&v;
        #pragma unroll
        for (int j = 0; j < 8; j++) a[j] = bf2f(u[j]);
    }
    unsigned p0 = offs[node], p1 = offs[node + 1];
    unsigned p = p0;
    for (; p + 4 <= p1; p += 4) {
        int s0 = col[p], s1 = col[p + 1], s2 = col[p + 2], s3 = col[p + 3];
        if (act) {
            uint4 v0 = *(const uint4*)(h2 + (size_t)s0 * NC + coff);
            uint4 v1 = *(const uint4*)(h2 + (size_t)s1 * NC + coff);
            uint4 v2 = *(const uint4*)(h2 + (size_t)s2 * NC + coff);
            uint4 v3 = *(const uint4*)(h2 + (size_t)s3 * NC + coff);
            const ushort* u0 = (const ushort*)&v0;
            const ushort* u1 = (const ushort*)&v1;
            const ushort* u2 = (const ushort*)&v2;
            const ushort* u3 = (const ushort*)&v3;
            #pragma unroll
            for (int j = 0; j < 8; j++)
                a[j] += (bf2f(u0[j]) + bf2f(u1[j])) + (bf2f(u2[j]) + bf2f(u3[j]));
        }
    }
    for (; p < p1; ++p) {
        int s = col[p];
        if (act) {
            uint4 v = *(const uint4*)(h2 + (size_t)s * NC + coff);
            const ushort* u = (const ushort*)&v;
            #pragma unroll
            for (int j = 0; j < 8; j++) a[j] += bf2f(u[j]);
        }
    }
    float dd = dis[node];
    float l[8];
    float m = -1e30f;
    if (act) {
        #pragma unroll
        for (int j = 0; j < 8; j++) {
            l[j] = a[j] * dd + b2[lane * 8 + j];
            m = fmaxf(m, l[j]);
        }
    }
    #pragma unroll
    for (int d = 1; d < 8; d <<= 1) m = fmaxf(m, __shfl_xor(m, d, 8));
    float s = 0.f;
    if (act) {
        #pragma unroll
        for (int j = 0; j < 8; j++) s += __expf(l[j] - m);
    }
    #pragma unroll
    for (int d = 1; d < 8; d <<= 1) s += __shfl_xor(s, d, 8);
    float lse = m + __logf(s);
    if (act) {
        float* op = out + (size_t)node * NC + lane * 8;
        *(float4*)op       = make_float4(l[0]-lse, l[1]-lse, l[2]-lse, l[3]-lse);
        *(float4*)(op + 4) = make_float4(l[4]-lse, l[5]-lse, l[6]-lse, l[7]-lse);
    }
}

extern "C" void kernel_launch(void* const* d_in, const int* in_sizes, int n_in,
                              void* d_out, int out_size, void* d_ws, size_t ws_size,
                              hipStream_t stream) {
    const float* x  = (const float*)d_in[0];
    const int*   ei = (const int*)d_in[1];
    const float* W1 = (const float*)d_in[2];
    const float* b1 = (const float*)d_in[3];
    const float* W2 = (const float*)d_in[4];
    const float* b2 = (const float*)d_in[5];
    float* out = (float*)d_out;

    const int N = in_sizes[0] / F_IN;     // 100000
    const int E = in_sizes[1] / 2;        // 1600000
    const int* src = ei;
    const int* dst = ei + E;

    // ---- workspace layout ----
    char* ws = (char*)d_ws;
    size_t o = 0;
    unsigned* cnt  = (unsigned*)(ws + o); o += (size_t)N * 4;
    unsigned* cur  = (unsigned*)(ws + o); o += (size_t)N * 4;   // contiguous w/ cnt
    float*    dis  = (float*)   (ws + o); o += (size_t)N * 4;
    unsigned* offs = (unsigned*)(ws + o); o += (size_t)(N + 4) * 4;
    unsigned* bsums= (unsigned*)(ws + o); o += 4096;
    int*      col  = (int*)     (ws + o); o += (size_t)E * 4;
    o = (o + 15) & ~(size_t)15;
    ushort*   W1p  = (ushort*)  (ws + o); o += (size_t)F_IN * HID * 2;   // 128 KB
    o = (o + 15) & ~(size_t)15;
    ushort*   W2p  = (ushort*)  (ws + o); o += 6144 * 2;                 // 12 KB
    o = (o + 15) & ~(size_t)15;
    ushort*   h1   = (ushort*)  (ws + o); o += (size_t)N * HID * 2;      // 25.6 MB
    o = (o + 15) & ~(size_t)15;
    ushort*   ag1  = (ushort*)  (ws + o); o += (size_t)N * HID * 2;      // 25.6 MB
    o = (o + 15) & ~(size_t)15;
    ushort*   h2   = (ushort*)  (ws + o); o += (size_t)N * NC * 2;       // 8 MB

    const int nb = (N + 1023) / 1024;

    // degree + CSR build (cnt and cur zeroed in one memset — contiguous)
    hipMemsetAsync(cnt, 0, (size_t)N * 8, stream);
    count_deg<<<(E + 255) / 256, 256, 0, stream>>>(dst, E, cnt);
    scan_block<<<nb, 1024, 0, stream>>>(cnt, offs, bsums, dis, N);
    scan_bsums<<<1, 1024, 0, stream>>>(bsums, nb);
    scan_add<<<nb, 1024, 0, stream>>>(offs, bsums, N, (unsigned)E);
    fill_csr<<<(E + 255) / 256, 256, 0, stream>>>(src, dst, offs, cur, col, E);

    // weight packs (merged)
    packW<<<(65536 + 6144 + 255) / 256, 256, 0, stream>>>(W1, W2, W1p, W2p);

    // layer 1 (128 rows per 256-thread block: 4 waves x 32 rows)
    gemm1_mfma<<<(N + 127) / 128, 256, 0, stream>>>(x, W1p, dis, h1, N);
    agg1_k<<<(N + 15) / 16, 256, 0, stream>>>(h1, col, offs, dis, b1, ag1, N);

    // layer 2
    gemm2_mfma<<<(N + 127) / 128, 256, 0, stream>>>(ag1, W2p, dis, h2, N);
    agg2_ls<<<(N + 31) / 32, 256, 0, stream>>>(h2, col, offs, dis, b2, out, N);
}